// Round 3
// baseline (305.894 us; speedup 1.0000x reference)
//
#include <hip/hip_runtime.h>

#define IMG   512
#define KSZ   11
#define HALO  5
#define BW    256                  // strip width = blockDim.x
#define BH    64                   // output rows per block
#define INW   (BW + 2*HALO)        // 266 staged columns
#define ROWS  (BH + 2*HALO)        // 74 input rows walked
#define CHUNK 11                   // rows staged per sync == ring depth

__global__ __launch_bounds__(256, 4)
void dssim_strip_kernel(const float* __restrict__ x,
                        const float* __restrict__ y,
                        const float* __restrict__ kern,
                        float* __restrict__ out)
{
    __shared__ float  sg[KSZ];
    __shared__ float2 sxy[CHUNK][INW + 1];   // x,y interleaved; 23.5 KB

    const int tid = threadIdx.x;

    // Recover separable 1D gaussian: row sums of the 2D kernel
    // (k2d[i][j] = g[i]*g[j], sum_j = g[i] since sum(g)==1).
    if (tid < KSZ) {
        float s = 0.f;
        #pragma unroll
        for (int j = 0; j < KSZ; ++j) s += kern[tid * KSZ + j];
        sg[tid] = s;
    }
    __syncthreads();

    // Symmetric taps: g[k] == g[10-k], keep only 6 in registers.
    float gk[HALO + 1];
    #pragma unroll
    for (int k = 0; k <= HALO; ++k) gk[k] = sg[k];

    const int plane = blockIdx.z;                   // n*C + c
    const long base = (long)plane * IMG * IMG;
    const int col0  = blockIdx.x * BW;
    const int row0  = blockIdx.y * BH;

    // Register ring buffer: 11 rows x 5 horizontally-blurred fields.
    float ring[CHUNK][5];

    const float C1 = 1e-4f;    // 0.01^2
    const float C2 = 9e-4f;    // 0.03^2
    float local = 0.f;

    for (int ii = 0; ii < ROWS; ii += CHUNK) {
        // ---- stage up to 11 input rows (x,y packed) into LDS ----
        // Row-wise: thread covers LDS col tid, and col tid+256 if tid<10.
        #pragma unroll
        for (int j = 0; j < CHUNK; ++j) {
            const int i = ii + j;
            if (i < ROWS) {
                const int gr  = row0 - HALO + i;
                const bool rok = (gr >= 0) && (gr < IMG);
                const long rbase = base + (long)gr * IMG;

                int gc = col0 - HALO + tid;
                float xv = 0.f, yv = 0.f;
                if (rok && gc >= 0 && gc < IMG) {
                    xv = x[rbase + gc];
                    yv = y[rbase + gc];
                }
                sxy[j][tid] = make_float2(xv, yv);

                if (tid < INW - BW) {
                    gc += BW;
                    float xv2 = 0.f, yv2 = 0.f;
                    if (rok && gc < IMG) {
                        xv2 = x[rbase + gc];
                        yv2 = y[rbase + gc];
                    }
                    sxy[j][tid + BW] = make_float2(xv2, yv2);
                }
            }
        }
        __syncthreads();

        // ---- process the staged rows ----
        #pragma unroll
        for (int j = 0; j < CHUNK; ++j) {
            const int i = ii + j;                  // input-row index (uniform)
            if (i < ROWS) {
                // horizontal 11-tap blur (ds_read_b64 per tap: x,y together)
                float ax = 0.f, ay = 0.f, axx = 0.f, ayy = 0.f, axy = 0.f;
                #pragma unroll
                for (int k = 0; k < KSZ; ++k) {
                    const float g  = gk[(k <= HALO) ? k : (KSZ - 1 - k)];
                    const float2 v = sxy[j][tid + k];
                    const float xv = v.x, yv = v.y;
                    ax  += g * xv;
                    ay  += g * yv;
                    axx += g * xv * xv;
                    ayy += g * yv * yv;
                    axy += g * xv * yv;
                }
                ring[j][0] = ax;  ring[j][1] = ay;
                ring[j][2] = axx; ring[j][3] = ayy; ring[j][4] = axy;

                // vertical 11-tap over the ring (registers only)
                if (i >= 2 * HALO) {
                    float mx = 0.f, my = 0.f, exx = 0.f, eyy = 0.f, exy = 0.f;
                    #pragma unroll
                    for (int k = 0; k < KSZ; ++k) {
                        const int s   = (j + 1 + k) % CHUNK;           // static
                        const float g = gk[(k <= HALO) ? k : (KSZ - 1 - k)];
                        mx  += g * ring[s][0];
                        my  += g * ring[s][1];
                        exx += g * ring[s][2];
                        eyy += g * ring[s][3];
                        exy += g * ring[s][4];
                    }
                    const float sxv = exx - mx * mx;
                    const float syv = eyy - my * my;
                    const float sxy_ = exy - mx * my;
                    const float num = (2.f * mx * my + C1) * (2.f * sxy_ + C2);
                    const float den = (mx * mx + my * my + C1) * (sxv + syv + C2);
                    const float ssim = __fdividef(num, den + 1e-8f);
                    local += (1.f - ssim) * 0.5f;
                }
            }
        }
        __syncthreads();   // WAR: ring done reading LDS before next stage
    }

    // ---- block reduction, one atomic per block ----
    #pragma unroll
    for (int o = 32; o > 0; o >>= 1) local += __shfl_down(local, o, 64);
    __shared__ float wsum[4];
    if ((tid & 63) == 0) wsum[tid >> 6] = local;
    __syncthreads();
    if (tid == 0) {
        const float s = wsum[0] + wsum[1] + wsum[2] + wsum[3];
        atomicAdd(out, s * (1.f / 25165824.f));   // / (32*3*512*512)
    }
}

extern "C" void kernel_launch(void* const* d_in, const int* in_sizes, int n_in,
                              void* d_out, int out_size, void* d_ws, size_t ws_size,
                              hipStream_t stream)
{
    const float* x    = (const float*)d_in[0];
    const float* y    = (const float*)d_in[1];
    const float* kern = (const float*)d_in[2];
    float* out = (float*)d_out;

    hipMemsetAsync(out, 0, sizeof(float), stream);

    dim3 grid(IMG / BW, IMG / BH, 32 * 3);   // 2 x 8 x 96 = 1536 blocks
    dssim_strip_kernel<<<grid, BW, 0, stream>>>(x, y, kern, out);
}

// Round 4
// 255.976 us; speedup vs baseline: 1.1950x; 1.1950x over previous
//
#include <hip/hip_runtime.h>

#define IMG   512
#define KSZ   11
#define HALO  5
#define BW    256                  // strip width = blockDim.x
#define BH    64                   // output rows per block
#define INW   (BW + 2*HALO)        // 266 staged columns
#define ROWS  (BH + 2*HALO)        // 74 input rows walked
#define CHUNK 11                   // rows staged per sync == ring depth

// NOTE: no min-waves arg! __launch_bounds__(256,4) forced VGPR=64 and
// spilled the 55-reg ring buffer to scratch (WRITE_SIZE 24B -> 110MB).
__global__ __launch_bounds__(256)
void dssim_strip_kernel(const float* __restrict__ x,
                        const float* __restrict__ y,
                        const float* __restrict__ kern,
                        float* __restrict__ out)
{
    __shared__ float  sg[KSZ];
    __shared__ float2 sxy[CHUNK][INW + 1];   // x,y interleaved; 23.5 KB

    const int tid = threadIdx.x;

    // Recover separable 1D gaussian: row sums of the 2D kernel
    // (k2d[i][j] = g[i]*g[j], sum_j = g[i] since sum(g)==1).
    if (tid < KSZ) {
        float s = 0.f;
        #pragma unroll
        for (int j = 0; j < KSZ; ++j) s += kern[tid * KSZ + j];
        sg[tid] = s;
    }
    __syncthreads();

    // Symmetric taps: g[k] == g[10-k], keep only 6 in registers.
    float gk[HALO + 1];
    #pragma unroll
    for (int k = 0; k <= HALO; ++k) gk[k] = sg[k];

    const int plane = blockIdx.z;                   // n*C + c
    const long base = (long)plane * IMG * IMG;
    const int col0  = blockIdx.x * BW;
    const int row0  = blockIdx.y * BH;

    // Register ring buffer: 11 rows x 5 horizontally-blurred fields.
    float ring[CHUNK][5];

    const float C1 = 1e-4f;    // 0.01^2
    const float C2 = 9e-4f;    // 0.03^2
    float local = 0.f;

    for (int ii = 0; ii < ROWS; ii += CHUNK) {
        // ---- stage up to 11 input rows (x,y packed) into LDS ----
        // Row-wise: thread covers LDS col tid, and col tid+256 if tid<10.
        #pragma unroll
        for (int j = 0; j < CHUNK; ++j) {
            const int i = ii + j;
            if (i < ROWS) {
                const int gr  = row0 - HALO + i;
                const bool rok = (gr >= 0) && (gr < IMG);
                const long rbase = base + (long)gr * IMG;

                int gc = col0 - HALO + tid;
                float xv = 0.f, yv = 0.f;
                if (rok && gc >= 0 && gc < IMG) {
                    xv = x[rbase + gc];
                    yv = y[rbase + gc];
                }
                sxy[j][tid] = make_float2(xv, yv);

                if (tid < INW - BW) {
                    gc += BW;
                    float xv2 = 0.f, yv2 = 0.f;
                    if (rok && gc < IMG) {
                        xv2 = x[rbase + gc];
                        yv2 = y[rbase + gc];
                    }
                    sxy[j][tid + BW] = make_float2(xv2, yv2);
                }
            }
        }
        __syncthreads();

        // ---- process the staged rows ----
        #pragma unroll
        for (int j = 0; j < CHUNK; ++j) {
            const int i = ii + j;                  // input-row index (uniform)
            if (i < ROWS) {
                // horizontal 11-tap blur (ds_read_b64 per tap: x,y together)
                float ax = 0.f, ay = 0.f, axx = 0.f, ayy = 0.f, axy = 0.f;
                #pragma unroll
                for (int k = 0; k < KSZ; ++k) {
                    const float g  = gk[(k <= HALO) ? k : (KSZ - 1 - k)];
                    const float2 v = sxy[j][tid + k];
                    const float xv = v.x, yv = v.y;
                    ax  += g * xv;
                    ay  += g * yv;
                    axx += g * xv * xv;
                    ayy += g * yv * yv;
                    axy += g * xv * yv;
                }
                ring[j][0] = ax;  ring[j][1] = ay;
                ring[j][2] = axx; ring[j][3] = ayy; ring[j][4] = axy;

                // vertical 11-tap over the ring (registers only)
                if (i >= 2 * HALO) {
                    float mx = 0.f, my = 0.f, exx = 0.f, eyy = 0.f, exy = 0.f;
                    #pragma unroll
                    for (int k = 0; k < KSZ; ++k) {
                        const int s   = (j + 1 + k) % CHUNK;           // static
                        const float g = gk[(k <= HALO) ? k : (KSZ - 1 - k)];
                        mx  += g * ring[s][0];
                        my  += g * ring[s][1];
                        exx += g * ring[s][2];
                        eyy += g * ring[s][3];
                        exy += g * ring[s][4];
                    }
                    const float sxv = exx - mx * mx;
                    const float syv = eyy - my * my;
                    const float sxy_ = exy - mx * my;
                    const float num = (2.f * mx * my + C1) * (2.f * sxy_ + C2);
                    const float den = (mx * mx + my * my + C1) * (sxv + syv + C2);
                    const float ssim = __fdividef(num, den + 1e-8f);
                    local += (1.f - ssim) * 0.5f;
                }
            }
        }
        __syncthreads();   // WAR: ring done reading LDS before next stage
    }

    // ---- block reduction, one atomic per block ----
    #pragma unroll
    for (int o = 32; o > 0; o >>= 1) local += __shfl_down(local, o, 64);
    __shared__ float wsum[4];
    if ((tid & 63) == 0) wsum[tid >> 6] = local;
    __syncthreads();
    if (tid == 0) {
        const float s = wsum[0] + wsum[1] + wsum[2] + wsum[3];
        atomicAdd(out, s * (1.f / 25165824.f));   // / (32*3*512*512)
    }
}

extern "C" void kernel_launch(void* const* d_in, const int* in_sizes, int n_in,
                              void* d_out, int out_size, void* d_ws, size_t ws_size,
                              hipStream_t stream)
{
    const float* x    = (const float*)d_in[0];
    const float* y    = (const float*)d_in[1];
    const float* kern = (const float*)d_in[2];
    float* out = (float*)d_out;

    hipMemsetAsync(out, 0, sizeof(float), stream);

    dim3 grid(IMG / BW, IMG / BH, 32 * 3);   // 2 x 8 x 96 = 1536 blocks
    dssim_strip_kernel<<<grid, BW, 0, stream>>>(x, y, kern, out);
}

// Round 5
// 173.342 us; speedup vs baseline: 1.7647x; 1.4767x over previous
//
#include <hip/hip_runtime.h>

#define IMG    512
#define KSZ    11
#define HALO   5
#define BW     256                  // strip width = blockDim.x
#define BH     128                  // output rows per block
#define INW    (BW + 2*HALO)        // 266 staged columns
#define ROWS   (BH + 2*HALO)        // 138 input rows walked
#define CHUNK  11                   // rows staged per buffer == ring depth
#define NCHUNK ((ROWS + CHUNK - 1) / CHUNK)   // 13

// No min-waves arg (round-3 lesson: (256,4) forced VGPR=64 -> ring spilled).
__global__ __launch_bounds__(256)
void dssim_strip_kernel(const float* __restrict__ x,
                        const float* __restrict__ y,
                        const float* __restrict__ kern,
                        float* __restrict__ out)
{
    __shared__ float  sg[KSZ];
    __shared__ float2 sxy[2][CHUNK][INW + 1];   // double-buffered, 2 x 23.5 KB

    const int tid = threadIdx.x;

    // Recover separable 1D gaussian: row sums of the 2D kernel
    // (k2d[i][j] = g[i]*g[j], sum_j = g[i] since sum(g)==1).
    if (tid < KSZ) {
        float s = 0.f;
        #pragma unroll
        for (int j = 0; j < KSZ; ++j) s += kern[tid * KSZ + j];
        sg[tid] = s;
    }
    __syncthreads();

    // Symmetric taps: g[k] == g[10-k].
    float gk[HALO + 1];
    #pragma unroll
    for (int k = 0; k <= HALO; ++k) gk[k] = sg[k];

    const int plane = blockIdx.z;                   // n*C + c
    const long base = (long)plane * IMG * IMG;
    const int col0  = blockIdx.x * BW;
    const int row0  = blockIdx.y * BH;

    // This thread's staged column (computed once).
    const int  gc  = col0 - HALO + tid;             // may be OOB at image edge
    const bool cok = (gc >= 0) && (gc < IMG);
    // Remainder columns (INW-BW=10 per row) flattened over threads 0..109:
    const bool eact = (tid < (INW - BW) * CHUNK);
    const int  je   = tid / (INW - BW);             // chunk-local row 0..10
    const int  ce   = BW + tid % (INW - BW);        // LDS col 256..265
    const int  gce  = col0 - HALO + ce;
    const bool ceok = eact && (gce >= 0) && (gce < IMG);

    // Register ring: 11 rows x 5 horizontally-blurred fields (static idx).
    float ring[CHUNK][5];
    // Prefetch registers for the next chunk (T14 issue-early / write-late).
    float2 pf[CHUNK];
    float2 pfe;

    const float C1 = 1e-4f;    // 0.01^2
    const float C2 = 9e-4f;    // 0.03^2
    float local = 0.f;

    // ---- prefetch chunk cc's rows into registers (global loads only) ----
    auto prefetch = [&](int cc) {
        #pragma unroll
        for (int j = 0; j < CHUNK; ++j) {
            const int i  = cc * CHUNK + j;
            const int gr = row0 - HALO + i;
            float xv = 0.f, yv = 0.f;
            if (i < ROWS && gr >= 0 && gr < IMG && cok) {
                const long off = base + (long)gr * IMG + gc;
                xv = x[off];
                yv = y[off];
            }
            pf[j] = make_float2(xv, yv);
        }
        const int ie  = cc * CHUNK + je;
        const int gre = row0 - HALO + ie;
        float xv = 0.f, yv = 0.f;
        if (ceok && ie < ROWS && gre >= 0 && gre < IMG) {
            const long off = base + (long)gre * IMG + gce;
            xv = x[off];
            yv = y[off];
        }
        pfe = make_float2(xv, yv);
    };

    // ---- write prefetched registers into LDS buffer b ----
    auto commit = [&](int b) {
        #pragma unroll
        for (int j = 0; j < CHUNK; ++j) sxy[b][j][tid] = pf[j];
        if (eact) sxy[b][je][ce] = pfe;
    };

    prefetch(0);
    commit(0);
    __syncthreads();

    for (int it = 0; it < NCHUNK; ++it) {
        const int cur = it & 1;

        // Issue next chunk's HBM loads NOW; they land during compute below.
        if (it + 1 < NCHUNK) prefetch(it + 1);

        // ---- compute current chunk from buf[cur] ----
        #pragma unroll
        for (int j = 0; j < CHUNK; ++j) {
            const int i = it * CHUNK + j;          // input-row index (uniform)
            if (i < ROWS) {
                // horizontal 11-tap blur (ds_read_b64 per tap)
                float ax = 0.f, ay = 0.f, axx = 0.f, ayy = 0.f, axy = 0.f;
                #pragma unroll
                for (int k = 0; k < KSZ; ++k) {
                    const float g  = gk[(k <= HALO) ? k : (KSZ - 1 - k)];
                    const float2 v = sxy[cur][j][tid + k];
                    ax  += g * v.x;
                    ay  += g * v.y;
                    axx += g * v.x * v.x;
                    ayy += g * v.y * v.y;
                    axy += g * v.x * v.y;
                }
                ring[j][0] = ax;  ring[j][1] = ay;
                ring[j][2] = axx; ring[j][3] = ayy; ring[j][4] = axy;

                // vertical 11-tap over the ring (registers only)
                if (i >= 2 * HALO) {
                    float mx = 0.f, my = 0.f, exx = 0.f, eyy = 0.f, exy = 0.f;
                    #pragma unroll
                    for (int k = 0; k < KSZ; ++k) {
                        const int s   = (j + 1 + k) % CHUNK;           // static
                        const float g = gk[(k <= HALO) ? k : (KSZ - 1 - k)];
                        mx  += g * ring[s][0];
                        my  += g * ring[s][1];
                        exx += g * ring[s][2];
                        eyy += g * ring[s][3];
                        exy += g * ring[s][4];
                    }
                    const float sxv  = exx - mx * mx;
                    const float syv  = eyy - my * my;
                    const float sxy_ = exy - mx * my;
                    const float num  = (2.f * mx * my + C1) * (2.f * sxy_ + C2);
                    const float den  = (mx * mx + my * my + C1) * (sxv + syv + C2);
                    const float ssim = __fdividef(num, den + 1e-8f);
                    local += (1.f - ssim) * 0.5f;
                }
            }
        }

        // Write next chunk into the OTHER buffer. Safe without a pre-barrier:
        // its last readers were fenced by the barrier at the end of it-1.
        if (it + 1 < NCHUNK) commit((it + 1) & 1);
        __syncthreads();   // writes visible; also fences buf[cur] for it+1's commit
    }

    // ---- block reduction, one atomic per block ----
    #pragma unroll
    for (int o = 32; o > 0; o >>= 1) local += __shfl_down(local, o, 64);
    __shared__ float wsum[4];
    if ((tid & 63) == 0) wsum[tid >> 6] = local;
    __syncthreads();
    if (tid == 0) {
        const float s = wsum[0] + wsum[1] + wsum[2] + wsum[3];
        atomicAdd(out, s * (1.f / 25165824.f));   // / (32*3*512*512)
    }
}

extern "C" void kernel_launch(void* const* d_in, const int* in_sizes, int n_in,
                              void* d_out, int out_size, void* d_ws, size_t ws_size,
                              hipStream_t stream)
{
    const float* x    = (const float*)d_in[0];
    const float* y    = (const float*)d_in[1];
    const float* kern = (const float*)d_in[2];
    float* out = (float*)d_out;

    hipMemsetAsync(out, 0, sizeof(float), stream);

    dim3 grid(IMG / BW, IMG / BH, 32 * 3);   // 2 x 4 x 96 = 768 = exactly 3/CU
    dssim_strip_kernel<<<grid, BW, 0, stream>>>(x, y, kern, out);
}

// Round 6
// 120.675 us; speedup vs baseline: 2.5349x; 1.4364x over previous
//
#include <hip/hip_runtime.h>

#define IMG    512
#define KSZ    11
#define HALO   5
#define BW     256                  // strip width = blockDim.x
#define BH     128                  // output rows per block
#define INW    (BW + 2*HALO)        // 266 staged columns
#define ROWS   (BH + 2*HALO)        // 138 input rows walked
#define CHUNK  11                   // rows staged per buffer == ring depth
#define NCHUNK ((ROWS + CHUNK - 1) / CHUNK)   // 13

// Packed fp32: one instruction does the x-lane and y-lane op together.
__device__ __forceinline__ float2 pk_fma(float2 a, float2 b, float2 c) {
    float2 d;
    asm("v_pk_fma_f32 %0, %1, %2, %3" : "=v"(d) : "v"(a), "v"(b), "v"(c));
    return d;
}
__device__ __forceinline__ float2 pk_mul(float2 a, float2 b) {
    float2 d;
    asm("v_pk_mul_f32 %0, %1, %2" : "=v"(d) : "v"(a), "v"(b));
    return d;
}

// No min-waves arg (round-3 lesson: (256,4) forced VGPR=64 -> ring spilled).
__global__ __launch_bounds__(256)
void dssim_strip_kernel(const float* __restrict__ x,
                        const float* __restrict__ y,
                        const float* __restrict__ kern,
                        float* __restrict__ out)
{
    __shared__ float  sg[KSZ];
    __shared__ float2 sxy[2][CHUNK][INW + 1];   // double-buffered, 2 x 23.5 KB

    const int tid = threadIdx.x;

    // Recover separable 1D gaussian: row sums of the 2D kernel
    // (k2d[i][j] = g[i]*g[j], sum_j = g[i] since sum(g)==1).
    if (tid < KSZ) {
        float s = 0.f;
        #pragma unroll
        for (int j = 0; j < KSZ; ++j) s += kern[tid * KSZ + j];
        sg[tid] = s;
    }
    __syncthreads();

    // Symmetric taps: g[k]==g[10-k]; keep (g,g) pairs for pk ops.
    float2 gg[HALO + 1];
    #pragma unroll
    for (int k = 0; k <= HALO; ++k) gg[k] = make_float2(sg[k], sg[k]);

    const int plane = blockIdx.z;                   // n*C + c
    const long base = (long)plane * IMG * IMG;
    const int col0  = blockIdx.x * BW;
    const int row0  = blockIdx.y * BH;

    // This thread's staged column (computed once).
    const int  gc  = col0 - HALO + tid;
    const bool cok = (gc >= 0) && (gc < IMG);
    // Remainder columns (INW-BW=10 per row) flattened over threads 0..109:
    const bool eact = (tid < (INW - BW) * CHUNK);
    const int  je   = tid / (INW - BW);             // chunk-local row 0..10
    const int  ce   = BW + tid % (INW - BW);        // LDS col 256..265
    const int  gce  = col0 - HALO + ce;
    const bool ceok = eact && (gce >= 0) && (gce < IMG);

    // Register ring: 11 rows of {(ax,ay),(axx,ayy),axy} — static indexing.
    float2 ringA[CHUNK];   // mu_x, mu_y partial (H-blurred)
    float2 ringS[CHUNK];   // E[x^2], E[y^2] partial
    float  ringC[CHUNK];   // E[xy] partial
    // Prefetch registers for the next chunk (issue-early / write-late).
    float2 pf[CHUNK];
    float2 pfe;

    const float C1 = 1e-4f;    // 0.01^2
    const float C2 = 9e-4f;    // 0.03^2
    float local = 0.f;

    auto prefetch = [&](int cc) {
        #pragma unroll
        for (int j = 0; j < CHUNK; ++j) {
            const int i  = cc * CHUNK + j;
            const int gr = row0 - HALO + i;
            float xv = 0.f, yv = 0.f;
            if (i < ROWS && gr >= 0 && gr < IMG && cok) {
                const long off = base + (long)gr * IMG + gc;
                xv = x[off];
                yv = y[off];
            }
            pf[j] = make_float2(xv, yv);
        }
        const int ie  = cc * CHUNK + je;
        const int gre = row0 - HALO + ie;
        float xv = 0.f, yv = 0.f;
        if (ceok && ie < ROWS && gre >= 0 && gre < IMG) {
            const long off = base + (long)gre * IMG + gce;
            xv = x[off];
            yv = y[off];
        }
        pfe = make_float2(xv, yv);
    };

    auto commit = [&](int b) {
        #pragma unroll
        for (int j = 0; j < CHUNK; ++j) sxy[b][j][tid] = pf[j];
        if (eact) sxy[b][je][ce] = pfe;
    };

    prefetch(0);
    commit(0);
    __syncthreads();

    for (int it = 0; it < NCHUNK; ++it) {
        const int cur = it & 1;

        // Issue next chunk's HBM loads NOW; they land during compute below.
        if (it + 1 < NCHUNK) prefetch(it + 1);

        #pragma unroll
        for (int j = 0; j < CHUNK; ++j) {
            const int i = it * CHUNK + j;          // input-row index (uniform)
            if (i < ROWS) {
                // Horizontal 11-tap: 3 pk + mul + fma per tap (was 8 scalar).
                float2 A = make_float2(0.f, 0.f);   // (ax, ay)
                float2 S = make_float2(0.f, 0.f);   // (axx, ayy)
                float  axy = 0.f;
                #pragma unroll
                for (int k = 0; k < KSZ; ++k) {
                    const float2 g2 = gg[(k <= HALO) ? k : (KSZ - 1 - k)];
                    const float2 v  = sxy[cur][j][tid + k];
                    A = pk_fma(g2, v, A);
                    const float2 sq = pk_mul(v, v);
                    S = pk_fma(g2, sq, S);
                    axy = fmaf(g2.x, v.x * v.y, axy);
                }
                ringA[j] = A;
                ringS[j] = S;
                ringC[j] = axy;

                // Vertical 11-tap over the ring: 2 pk + 1 fma per tap (was 5).
                if (i >= 2 * HALO) {
                    float2 M = make_float2(0.f, 0.f);   // (mx, my)
                    float2 E = make_float2(0.f, 0.f);   // (exx, eyy)
                    float  exy = 0.f;
                    #pragma unroll
                    for (int k = 0; k < KSZ; ++k) {
                        const int s    = (j + 1 + k) % CHUNK;          // static
                        const float2 g2 = gg[(k <= HALO) ? k : (KSZ - 1 - k)];
                        M = pk_fma(g2, ringA[s], M);
                        E = pk_fma(g2, ringS[s], E);
                        exy = fmaf(g2.x, ringC[s], exy);
                    }
                    const float mx = M.x, my = M.y;
                    const float sxv  = E.x - mx * mx;
                    const float syv  = E.y - my * my;
                    const float sxy_ = exy - mx * my;
                    const float num  = (2.f * mx * my + C1) * (2.f * sxy_ + C2);
                    const float den  = (mx * mx + my * my + C1) * (sxv + syv + C2);
                    const float ssim = __fdividef(num, den + 1e-8f);
                    local += (1.f - ssim) * 0.5f;
                }
            }
        }

        // Write next chunk into the OTHER buffer (WAR fenced by prev barrier).
        if (it + 1 < NCHUNK) commit((it + 1) & 1);
        __syncthreads();
    }

    // ---- block reduction, one atomic per block ----
    #pragma unroll
    for (int o = 32; o > 0; o >>= 1) local += __shfl_down(local, o, 64);
    __shared__ float wsum[4];
    if ((tid & 63) == 0) wsum[tid >> 6] = local;
    __syncthreads();
    if (tid == 0) {
        const float s = wsum[0] + wsum[1] + wsum[2] + wsum[3];
        atomicAdd(out, s * (1.f / 25165824.f));   // / (32*3*512*512)
    }
}

extern "C" void kernel_launch(void* const* d_in, const int* in_sizes, int n_in,
                              void* d_out, int out_size, void* d_ws, size_t ws_size,
                              hipStream_t stream)
{
    const float* x    = (const float*)d_in[0];
    const float* y    = (const float*)d_in[1];
    const float* kern = (const float*)d_in[2];
    float* out = (float*)d_out;

    hipMemsetAsync(out, 0, sizeof(float), stream);

    dim3 grid(IMG / BW, IMG / BH, 32 * 3);   // 2 x 4 x 96 = 768 = exactly 3/CU
    dssim_strip_kernel<<<grid, BW, 0, stream>>>(x, y, kern, out);
}